// Round 5
// baseline (433.935 us; speedup 1.0000x reference)
//
#include <hip/hip_runtime.h>
#include <math.h>

typedef unsigned short u16;
typedef unsigned int u32;
typedef float f4 __attribute__((ext_vector_type(4)));
typedef short bf16x8 __attribute__((ext_vector_type(8)));
typedef float f32x4 __attribute__((ext_vector_type(4)));

#define S_LEN 2048
#define H_DIM 2880
#define NQD 4096
#define RANKD 384
#define HD 64
#define NH 64
#define NKV 8
#define RLN 0.37244970541f  /* ln(150000)/32 */

__device__ __forceinline__ u16 f2bf(float f) {
  u32 u = __float_as_uint(f);
  u += 0x7fffu + ((u >> 16) & 1u);
  return (u16)(u >> 16);
}

#define GLOAD_LDS(g, l) __builtin_amdgcn_global_load_lds( \
    (__attribute__((address_space(1))) void*)(g),          \
    (__attribute__((address_space(3))) void*)(l), 16, 0, 0)

// Fragment-linear K layout (A-operand of K@Q^T):
// u16 offset for element (kvh, s, d)
__device__ __forceinline__ size_t koff_s(int s) {
  return (size_t)((s >> 6) * 4096 + ((s >> 4) & 3) * 1024 + (s & 15) * 8);
}
__device__ __forceinline__ int koff_d(int d) {
  return (d >> 5) * 512 + ((d >> 3) & 3) * 128 + (d & 7);
}
// Fragment-linear V^T layout (B-operand of P@V):
__device__ __forceinline__ size_t voff_s(int s) {
  return (size_t)((s >> 6) * 4096 + ((s >> 5) & 1) * 512 + ((s >> 3) & 3) * 128 + (s & 7));
}
__device__ __forceinline__ int voff_d(int d) {
  return ((d >> 4) & 3) * 1024 + (d & 15) * 8;
}

// ---------------- fp32 -> bf16 convert ----------------
__global__ void conv_f2b(const float* __restrict__ in, u16* __restrict__ out, int n4) {
  int i = blockIdx.x * blockDim.x + threadIdx.x;
  if (i >= n4) return;
  f4 v = ((const f4*)in)[i];
  ushort4 o;
  o.x = f2bf(v[0]); o.y = f2bf(v[1]); o.z = f2bf(v[2]); o.w = f2bf(v[3]);
  ((ushort4*)out)[i] = o;
}

// ---------------- 128x128 MFMA GEMM: Q-projection (2-phase dbuf, BK=64) ----------------
// LDS layout: [dbuf][khalf][128][32] u16 for A and B.
// RoPE + 1/8 scale, bf16 out0[(head*S + s)*64 + d], head = col/64
__global__ __launch_bounds__(256) void gemm128(
    const u16* __restrict__ A, const u16* __restrict__ W,
    const float* __restrict__ bias, int K,
    u16* __restrict__ out0) {
  __shared__ __align__(16) u16 As[2 * 2 * 128 * 32];
  __shared__ __align__(16) u16 Bs[2 * 2 * 128 * 32];
  int t = threadIdx.x, w = t >> 6, L = t & 63;
  int lm = L & 15, quad = L >> 4;
  int m0 = blockIdx.x * 128, n0 = blockIdx.y * 128;
  int wm = w >> 1, wn = w & 1;
  int srow = L >> 2, scol8 = (L & 3) * 8;
  const u16* Ag0 = A + (size_t)(m0 + (w * 2) * 16 + srow) * K + scol8;
  const u16* Ag1 = Ag0 + (size_t)16 * K;
  const u16* Wg0 = W + (size_t)(n0 + (w * 2) * 16 + srow) * K + scol8;
  const u16* Wg1 = Wg0 + (size_t)16 * K;
  u16* lA0 = &As[(w * 2) * 512];
  u16* lA1 = &As[(w * 2 + 1) * 512];
  u16* lB0 = &Bs[(w * 2) * 512];
  u16* lB1 = &Bs[(w * 2 + 1) * 512];
  f32x4 acc[4][4] = {};
  int nk = K >> 6;   // BK = 64
  // prologue: stage K-tile 0 (both 32-halves) into buffer 0
  GLOAD_LDS(Ag0, lA0);           GLOAD_LDS(Ag1, lA1);
  GLOAD_LDS(Ag0 + 32, lA0 + 4096); GLOAD_LDS(Ag1 + 32, lA1 + 4096);
  GLOAD_LDS(Wg0, lB0);           GLOAD_LDS(Wg1, lB1);
  GLOAD_LDS(Wg0 + 32, lB0 + 4096); GLOAD_LDS(Wg1 + 32, lB1 + 4096);
  Ag0 += 64; Ag1 += 64; Wg0 += 64; Wg1 += 64;
  __syncthreads();
  for (int kt = 0; kt < nk; ++kt) {
    int cur = (kt & 1) << 13;     // 8192 u16 per dbuf slot
    int nxt = 8192 - cur;
    if (kt + 1 < nk) {
      GLOAD_LDS(Ag0, lA0 + nxt);           GLOAD_LDS(Ag1, lA1 + nxt);
      GLOAD_LDS(Ag0 + 32, lA0 + nxt + 4096); GLOAD_LDS(Ag1 + 32, lA1 + nxt + 4096);
      GLOAD_LDS(Wg0, lB0 + nxt);           GLOAD_LDS(Wg1, lB1 + nxt);
      GLOAD_LDS(Wg0 + 32, lB0 + nxt + 4096); GLOAD_LDS(Wg1 + 32, lB1 + nxt + 4096);
      Ag0 += 64; Ag1 += 64; Wg0 += 64; Wg1 += 64;
    }
#pragma unroll
    for (int h = 0; h < 2; ++h) {
      int base = cur + h * 4096;
      bf16x8 af[4], bf[4];
#pragma unroll
      for (int i = 0; i < 4; ++i) af[i] = *(const bf16x8*)&As[base + (wm * 64 + i * 16 + lm) * 32 + quad * 8];
#pragma unroll
      for (int j = 0; j < 4; ++j) bf[j] = *(const bf16x8*)&Bs[base + (wn * 64 + j * 16 + lm) * 32 + quad * 8];
#pragma unroll
      for (int i = 0; i < 4; ++i)
#pragma unroll
        for (int j = 0; j < 4; ++j)
          acc[i][j] = __builtin_amdgcn_mfma_f32_16x16x32_bf16(af[i], bf[j], acc[i][j], 0, 0, 0);
    }
    __syncthreads();
  }
  int head = (n0 + wn * 64) >> 6;
  float b0v = bias[head * 64 + lm];
  float b1v = bias[head * 64 + 16 + lm];
  float b2v = bias[head * 64 + 32 + lm];
  float b3v = bias[head * 64 + 48 + lm];
  float invf1 = __expf(-(float)lm * RLN);
  float invf2 = __expf(-(float)(lm + 16) * RLN);
#pragma unroll
  for (int i = 0; i < 4; ++i) {
    int sq = m0 + wm * 64 + i * 16 + quad * 4;
#pragma unroll
    for (int r = 0; r < 4; ++r) {
      float a0 = acc[i][0][r] + b0v, a1 = acc[i][1][r] + b1v;
      float a2 = acc[i][2][r] + b2v, a3 = acc[i][3][r] + b3v;
      float s1, c1, s2, c2;
      sincosf((float)(sq + r) * invf1, &s1, &c1);
      sincosf((float)(sq + r) * invf2, &s2, &c2);
      u16* op = out0 + ((size_t)head * S_LEN + sq + r) * HD;
      op[lm]      = f2bf((a0 * c1 - a2 * s1) * 0.125f);
      op[lm + 32] = f2bf((a2 * c1 + a0 * s1) * 0.125f);
      op[lm + 16] = f2bf((a1 * c2 - a3 * s2) * 0.125f);
      op[lm + 48] = f2bf((a3 * c2 + a1 * s2) * 0.125f);
    }
  }
}

// ---------------- 64x128 MFMA GEMM: O-projection (2-phase dbuf, BK=64, fp32 out + bias) ----------------
// LDS layout: A [dbuf][khalf][64][32], B [dbuf][khalf][128][32].
__global__ __launch_bounds__(256) void gemm64(
    const u16* __restrict__ A, const u16* __restrict__ W,
    const float* __restrict__ bias, int K, int Nreal,
    float* __restrict__ out) {
  __shared__ __align__(16) u16 As[2 * 2 * 64 * 32];
  __shared__ __align__(16) u16 Bs[2 * 2 * 128 * 32];
  int t = threadIdx.x, w = t >> 6, L = t & 63;
  int lm = L & 15, quad = L >> 4;
  int m0 = blockIdx.x * 64, n0 = blockIdx.y * 128;
  int wm = w >> 1, wn = w & 1;
  int srow = L >> 2, scol8 = (L & 3) * 8;
  const u16* Ag = A + (size_t)(m0 + w * 16 + srow) * K + scol8;
  int wr0 = n0 + w * 16 + srow;      if (wr0 > Nreal - 1) wr0 = Nreal - 1;
  int wr1 = n0 + 64 + w * 16 + srow; if (wr1 > Nreal - 1) wr1 = Nreal - 1;
  const u16* Wg0 = W + (size_t)wr0 * K + scol8;
  const u16* Wg1 = W + (size_t)wr1 * K + scol8;
  u16* lA  = &As[w * 512];
  u16* lB0 = &Bs[w * 512];
  u16* lB1 = &Bs[2048 + w * 512];
  f32x4 acc[2][4] = {};
  int nk = K >> 6;   // BK = 64
  // prologue: stage K-tile 0 (both 32-halves) into buffer 0
  GLOAD_LDS(Ag, lA);            GLOAD_LDS(Ag + 32, lA + 2048);
  GLOAD_LDS(Wg0, lB0);          GLOAD_LDS(Wg0 + 32, lB0 + 4096);
  GLOAD_LDS(Wg1, lB1);          GLOAD_LDS(Wg1 + 32, lB1 + 4096);
  Ag += 64; Wg0 += 64; Wg1 += 64;
  __syncthreads();
  for (int kt = 0; kt < nk; ++kt) {
    int curA = (kt & 1) << 12;    // 4096 u16 per A dbuf slot
    int curB = (kt & 1) << 13;    // 8192 u16 per B dbuf slot
    int nxtA = 4096 - curA, nxtB = 8192 - curB;
    if (kt + 1 < nk) {
      GLOAD_LDS(Ag, lA + nxtA);          GLOAD_LDS(Ag + 32, lA + nxtA + 2048);
      GLOAD_LDS(Wg0, lB0 + nxtB);        GLOAD_LDS(Wg0 + 32, lB0 + nxtB + 4096);
      GLOAD_LDS(Wg1, lB1 + nxtB);        GLOAD_LDS(Wg1 + 32, lB1 + nxtB + 4096);
      Ag += 64; Wg0 += 64; Wg1 += 64;
    }
#pragma unroll
    for (int h = 0; h < 2; ++h) {
      int baseA = curA + h * 2048;
      int baseB = curB + h * 4096;
      bf16x8 af[2], bf[4];
#pragma unroll
      for (int i = 0; i < 2; ++i) af[i] = *(const bf16x8*)&As[baseA + (wm * 32 + i * 16 + lm) * 32 + quad * 8];
#pragma unroll
      for (int j = 0; j < 4; ++j) bf[j] = *(const bf16x8*)&Bs[baseB + (wn * 64 + j * 16 + lm) * 32 + quad * 8];
#pragma unroll
      for (int i = 0; i < 2; ++i)
#pragma unroll
        for (int j = 0; j < 4; ++j)
          acc[i][j] = __builtin_amdgcn_mfma_f32_16x16x32_bf16(af[i], bf[j], acc[i][j], 0, 0, 0);
    }
    __syncthreads();
  }
#pragma unroll
  for (int i = 0; i < 2; ++i) {
#pragma unroll
    for (int r = 0; r < 4; ++r) {
      int row = m0 + wm * 32 + i * 16 + quad * 4 + r;
#pragma unroll
      for (int j = 0; j < 4; ++j) {
        int col = n0 + wn * 64 + j * 16 + lm;
        if (col < Nreal)
          out[(size_t)row * Nreal + col] = acc[i][j][r] + bias[col];
      }
    }
  }
}

// ---------------- 64x64 MFMA GEMM for the two small KV GEMMs ----------------
// mode 2: KV: even n-tiles = K half (RoPE -> fragment-linear K layout),
//             odd = V half (-> fragment-linear V^T layout), kvh = n0/128
// mode 3: bf16 row-major out0
__global__ __launch_bounds__(256) void gemm_bt(
    const u16* __restrict__ A, const u16* __restrict__ W,
    int M, int N, int K, int mode,
    u16* __restrict__ out0, u16* __restrict__ out1) {
  __shared__ __align__(16) u16 As[64 * 32];
  __shared__ __align__(16) u16 Bs[64 * 32];
  int t = threadIdx.x;
  int m0 = blockIdx.x * 64, n0 = blockIdx.y * 64;
  int w = t >> 6, L = t & 63;
  int srow = t >> 2, scol = (t & 3) * 8;
  int lm = L & 15, quad = L >> 4;
  const u16* Ap = A + (size_t)(m0 + srow) * K + scol;
  const u16* Wp = W + (size_t)(n0 + srow) * K + scol;
  f32x4 acc0 = {0.f, 0.f, 0.f, 0.f}, acc1 = acc0, acc2 = acc0, acc3 = acc0;
  int aoff = (w * 16 + lm) * 32 + quad * 8;
  int boff = lm * 32 + quad * 8;
  int nk = K >> 5;
  uint4 av = *(const uint4*)Ap;
  uint4 wv = *(const uint4*)Wp;
  for (int kt = 0; kt < nk; ++kt) {
    *(uint4*)&As[srow * 32 + scol] = av;
    *(uint4*)&Bs[srow * 32 + scol] = wv;
    __syncthreads();
    if (kt + 1 < nk) {
      Ap += 32; Wp += 32;
      av = *(const uint4*)Ap;
      wv = *(const uint4*)Wp;
    }
    bf16x8 af = *(const bf16x8*)&As[aoff];
    bf16x8 b0 = *(const bf16x8*)&Bs[boff];
    bf16x8 b1 = *(const bf16x8*)&Bs[boff + 16 * 32];
    bf16x8 b2 = *(const bf16x8*)&Bs[boff + 32 * 32];
    bf16x8 b3 = *(const bf16x8*)&Bs[boff + 48 * 32];
    acc0 = __builtin_amdgcn_mfma_f32_16x16x32_bf16(af, b0, acc0, 0, 0, 0);
    acc1 = __builtin_amdgcn_mfma_f32_16x16x32_bf16(af, b1, acc1, 0, 0, 0);
    acc2 = __builtin_amdgcn_mfma_f32_16x16x32_bf16(af, b2, acc2, 0, 0, 0);
    acc3 = __builtin_amdgcn_mfma_f32_16x16x32_bf16(af, b3, acc3, 0, 0, 0);
    __syncthreads();
  }
  int mbase = m0 + w * 16 + quad * 4;
  if (mode == 3) {
    for (int r = 0; r < 4; ++r) {
      int row = mbase + r;
      float vals[4] = {acc0[r], acc1[r], acc2[r], acc3[r]};
      for (int nt = 0; nt < 4; ++nt)
        out0[(size_t)row * N + (n0 + nt * 16 + lm)] = f2bf(vals[nt]);
    }
  } else {
    bool isV = ((blockIdx.y & 1) == 1);
    int head = (n0 >> 7);
    size_t hb = (size_t)head << 17;
    if (isV) {
      // V -> fragment-linear V^T layout
      int dof[4];
#pragma unroll
      for (int nt = 0; nt < 4; ++nt) dof[nt] = voff_d(nt * 16 + lm);
      for (int r = 0; r < 4; ++r) {
        int s = mbase + r;
        size_t so = hb + voff_s(s);
        float vals[4] = {acc0[r], acc1[r], acc2[r], acc3[r]};
#pragma unroll
        for (int nt = 0; nt < 4; ++nt)
          out1[so + dof[nt]] = f2bf(vals[nt]);
      }
    } else {
      // K -> RoPE -> fragment-linear K layout
      int d0 = koff_d(lm), d1 = koff_d(lm + 16), d2 = koff_d(lm + 32), d3 = koff_d(lm + 48);
      float invf1 = __expf(-(float)lm * RLN);
      float invf2 = __expf(-(float)(lm + 16) * RLN);
      for (int r = 0; r < 4; ++r) {
        int s = mbase + r;
        float a0 = acc0[r], a1 = acc1[r], a2 = acc2[r], a3 = acc3[r];
        float s1, c1, s2, c2;
        sincosf((float)s * invf1, &s1, &c1);
        sincosf((float)s * invf2, &s2, &c2);
        size_t so = hb + koff_s(s);
        out0[so + d0] = f2bf(a0 * c1 - a2 * s1);
        out0[so + d2] = f2bf(a2 * c1 + a0 * s1);
        out0[so + d1] = f2bf(a1 * c2 - a3 * s2);
        out0[so + d3] = f2bf(a3 * c2 + a1 * s2);
      }
    }
  }
}

// ---------------- MFMA flash attention v4 ----------------
// v3 + (1) K-fragment prefetch rotation: kf regs reloaded for c+1 right after
// QK(c) consumes them -> K load latency hidden under softmax+PV;
// (2) v_cvt_pk_bf16_f32 for P packing (replaces 16x manual-RNE f2bf + or/shift);
// (3) defer-max (THR=8): skip O-rescale + keep running max when tile max
// growth <= 8 (wave-uniform via __all; P bounded by e^8, safe in bf16).
__global__ __launch_bounds__(256, 4) void attn_v3(
    const u16* __restrict__ Qb, const u16* __restrict__ Kf,
    const u16* __restrict__ Vf, u16* __restrict__ attnb) {
  __shared__ __align__(16) u16 Ps[4 * 16 * 72];  // per-wave P, row stride 72 u16
  int t = threadIdx.x;
  int w = t >> 6, L = t & 63;
  int lm = L & 15, quad = L >> 4;
  int bx = blockIdx.x, h = blockIdx.y, kvh = h >> 3;
  u16* pw = &Ps[w * 16 * 72];
  const u16* Kbase = Kf + ((size_t)kvh << 17) + L * 8;
  const u16* Vbase = Vf + ((size_t)kvh << 17) + L * 8;

  for (int ph = 0; ph < 2; ++ph) {
    int qt = ph ? (31 - bx) : bx;
    int q0 = qt * 64;
    // Q B-fragments: lane holds Q[q0+w*16+lm][quad*8+e] (halves 0/1)
    const u16* Qp = Qb + ((size_t)h * S_LEN + q0 + w * 16 + lm) * HD + quad * 8;
    bf16x8 qf0 = *(const bf16x8*)Qp;
    bf16x8 qf1 = *(const bf16x8*)(Qp + 32);
    f32x4 o[4] = {};
    float m_ = -3.0e38f, l_ = 0.f;

    // ---- K fragments for c=0 (prefetch rotation primes here) ----
    bf16x8 kfa[4], kfb[4];
#pragma unroll
    for (int j = 0; j < 4; ++j) {
      kfa[j] = *(const bf16x8*)(Kbase + j * 1024);
      kfb[j] = *(const bf16x8*)(Kbase + j * 1024 + 512);
    }

    for (int c = 0; c <= qt; ++c) {
      // ---- S^T = K Q^T : tile j rows kv=j*16+quad*4+r, col q=lm ----
      f32x4 st[4] = {};
#pragma unroll
      for (int j = 0; j < 4; ++j) {
        st[j] = __builtin_amdgcn_mfma_f32_16x16x32_bf16(kfa[j], qf0, st[j], 0, 0, 0);
        st[j] = __builtin_amdgcn_mfma_f32_16x16x32_bf16(kfb[j], qf1, st[j], 0, 0, 0);
      }
      // ---- prefetch K(c+1) into same regs (WAR after MFMA issue) ----
      if (c < qt) {
        const u16* Kn = Kbase + (size_t)(c + 1) * 4096;
#pragma unroll
        for (int j = 0; j < 4; ++j) {
          kfa[j] = *(const bf16x8*)(Kn + j * 1024);
          kfb[j] = *(const bf16x8*)(Kn + j * 1024 + 512);
        }
      }
      // ---- V fragments issued now (consumed after softmax) ----
      const u16* Vc = Vbase + (size_t)c * 4096;
      bf16x8 vfa[4], vfb[4];
#pragma unroll
      for (int j = 0; j < 4; ++j) {
        vfa[j] = *(const bf16x8*)(Vc + j * 1024);
        vfb[j] = *(const bf16x8*)(Vc + j * 1024 + 512);
      }
      // ---- causal mask on diagonal chunk ----
      if (c == qt) {
        int qloc = w * 16 + lm;
#pragma unroll
        for (int j = 0; j < 4; ++j) {
          int kvb = j * 16 + quad * 4;
#pragma unroll
          for (int r = 0; r < 4; ++r)
            if (kvb + r > qloc) st[j][r] = -3.0e38f;
        }
      }
      // ---- online softmax: each lane owns 16 scores of q-row lm ----
      float mloc = -3.0e38f;
#pragma unroll
      for (int j = 0; j < 4; ++j)
        mloc = fmaxf(mloc, fmaxf(fmaxf(st[j][0], st[j][1]), fmaxf(st[j][2], st[j][3])));
      mloc = fmaxf(mloc, __shfl_xor(mloc, 16));
      mloc = fmaxf(mloc, __shfl_xor(mloc, 32));
      float mn;
      if (__all(mloc - m_ <= 8.f)) {
        // defer: keep old max, no O/l rescale (P bounded by e^8)
        mn = m_;
      } else {
        mn = fmaxf(m_, mloc);
        float al = __expf(m_ - mn);
        m_ = mn;
        l_ *= al;
        float a0 = __shfl(al, quad * 4 + 0);
        float a1 = __shfl(al, quad * 4 + 1);
        float a2 = __shfl(al, quad * 4 + 2);
        float a3 = __shfl(al, quad * 4 + 3);
#pragma unroll
        for (int j = 0; j < 4; ++j) {
          o[j][0] *= a0; o[j][1] *= a1; o[j][2] *= a2; o[j][3] *= a3;
        }
      }
      float sum = 0.f;
      u16* pws = pw + lm * 72;
#pragma unroll
      for (int j = 0; j < 4; ++j) {
        float p0 = __expf(st[j][0] - mn);
        float p1 = __expf(st[j][1] - mn);
        float p2 = __expf(st[j][2] - mn);
        float p3 = __expf(st[j][3] - mn);
        sum += (p0 + p1) + (p2 + p3);
        uint2 pk;
        asm("v_cvt_pk_bf16_f32 %0, %1, %2" : "=v"(pk.x) : "v"(p0), "v"(p1));
        asm("v_cvt_pk_bf16_f32 %0, %1, %2" : "=v"(pk.y) : "v"(p2), "v"(p3));
        *(uint2*)(pws + j * 16 + quad * 4) = pk;
      }
      l_ += sum;
      // ---- P (A-layout) from LDS ----
      bf16x8 pa = *(const bf16x8*)(pw + lm * 72 + quad * 8);
      bf16x8 pb = *(const bf16x8*)(pw + lm * 72 + 32 + quad * 8);
      // ---- O += P V ----
#pragma unroll
      for (int j = 0; j < 4; ++j) {
        o[j] = __builtin_amdgcn_mfma_f32_16x16x32_bf16(pa, vfa[j], o[j], 0, 0, 0);
        o[j] = __builtin_amdgcn_mfma_f32_16x16x32_bf16(pb, vfb[j], o[j], 0, 0, 0);
      }
    }
    // ---- finalize ----
    l_ += __shfl_xor(l_, 16);
    l_ += __shfl_xor(l_, 32);
    float linv = 1.0f / l_;
    float li0 = __shfl(linv, quad * 4 + 0);
    float li1 = __shfl(linv, quad * 4 + 1);
    float li2 = __shfl(linv, quad * 4 + 2);
    float li3 = __shfl(linv, quad * 4 + 3);
#pragma unroll
    for (int r = 0; r < 4; ++r) {
      float lr = (r == 0) ? li0 : (r == 1) ? li1 : (r == 2) ? li2 : li3;
      int row = q0 + w * 16 + quad * 4 + r;
      u16* op = attnb + (size_t)row * NQD + h * HD;
      op[lm]      = f2bf(o[0][r] * lr);
      op[lm + 16] = f2bf(o[1][r] * lr);
      op[lm + 32] = f2bf(o[2][r] * lr);
      op[lm + 48] = f2bf(o[3][r] * lr);
    }
  }
}

extern "C" void kernel_launch(void* const* d_in, const int* in_sizes, int n_in,
                              void* d_out, int out_size, void* d_ws, size_t ws_size,
                              hipStream_t stream) {
  (void)in_sizes; (void)n_in; (void)out_size; (void)ws_size;
  const float* hidden = (const float*)d_in[0];
  // d_in[1] = attention_mask (exactly causal; handled analytically)
  const float* q_w    = (const float*)d_in[2];
  const float* q_b    = (const float*)d_in[3];
  const float* kv_a_w = (const float*)d_in[4];
  const float* kv_b_w = (const float*)d_in[5];
  const float* o_w    = (const float*)d_in[6];
  const float* o_b    = (const float*)d_in[7];

  char* ws = (char*)d_ws;
  u16* hb    = (u16*)(ws + 0);           // 2048x2880
  u16* qwb   = (u16*)(ws + 11796480);    // 4096x2880
  u16* kab   = (u16*)(ws + 35389440);    // 384x2880
  u16* kbb   = (u16*)(ws + 37601280);    // 1024x384
  u16* owb   = (u16*)(ws + 38387712);    // 2880x4096
  u16* Qb    = (u16*)(ws + 61980672);    // (64,2048,64) roped, pre-scaled 1/8
  u16* CKVb  = (u16*)(ws + 78757888);    // 2048x384
  u16* Kfb   = (u16*)(ws + 80330752);    // (8) fragment-linear K, 2MB
  u16* Vfb   = (u16*)(ws + 82427904);    // (8) fragment-linear V^T, 2MB
  u16* attnb = (u16*)(ws + 84525056);    // 2048x4096

  conv_f2b<<<(1474560 + 255) / 256, 256, 0, stream>>>(hidden, hb, 1474560);
  conv_f2b<<<(2949120 + 255) / 256, 256, 0, stream>>>(q_w, qwb, 2949120);
  conv_f2b<<<(276480 + 255) / 256, 256, 0, stream>>>(kv_a_w, kab, 276480);
  conv_f2b<<<(98304 + 255) / 256, 256, 0, stream>>>(kv_b_w, kbb, 98304);
  conv_f2b<<<(2949120 + 255) / 256, 256, 0, stream>>>(o_w, owb, 2949120);

  gemm128<<<dim3(16, 32), 256, 0, stream>>>(hb, qwb, q_b, H_DIM, Qb);
  gemm_bt<<<dim3(32, 6),  256, 0, stream>>>(hb, kab, S_LEN, RANKD, H_DIM, 3, CKVb, nullptr);
  gemm_bt<<<dim3(32, 16), 256, 0, stream>>>(CKVb, kbb, S_LEN, 1024, RANKD, 2, Kfb, Vfb);
  attn_v3<<<dim3(16, 64), 256, 0, stream>>>(Qb, Kfb, Vfb, attnb);
  gemm64<<<dim3(32, 23), 256, 0, stream>>>(attnb, owb, o_b, NQD, H_DIM, (float*)d_out);
}

// Round 6
// 411.579 us; speedup vs baseline: 1.0543x; 1.0543x over previous
//
#include <hip/hip_runtime.h>
#include <math.h>

typedef unsigned short u16;
typedef unsigned int u32;
typedef float f4 __attribute__((ext_vector_type(4)));
typedef short bf16x8 __attribute__((ext_vector_type(8)));
typedef float f32x4 __attribute__((ext_vector_type(4)));

#define S_LEN 2048
#define H_DIM 2880
#define NQD 4096
#define RANKD 384
#define HD 64
#define NH 64
#define NKV 8
#define RLN 0.37244970541f  /* ln(150000)/32 */

__device__ __forceinline__ u16 f2bf(float f) {
  u32 u = __float_as_uint(f);
  u += 0x7fffu + ((u >> 16) & 1u);
  return (u16)(u >> 16);
}

#define GLOAD_LDS(g, l) __builtin_amdgcn_global_load_lds( \
    (__attribute__((address_space(1))) void*)(g),          \
    (__attribute__((address_space(3))) void*)(l), 16, 0, 0)

// Fragment-linear K layout (A-operand of K@Q^T):
// u16 offset for element (kvh, s, d)
__device__ __forceinline__ size_t koff_s(int s) {
  return (size_t)((s >> 6) * 4096 + ((s >> 4) & 3) * 1024 + (s & 15) * 8);
}
__device__ __forceinline__ int koff_d(int d) {
  return (d >> 5) * 512 + ((d >> 3) & 3) * 128 + (d & 7);
}
// Fragment-linear V^T layout (B-operand of P@V):
__device__ __forceinline__ size_t voff_s(int s) {
  return (size_t)((s >> 6) * 4096 + ((s >> 5) & 1) * 512 + ((s >> 3) & 3) * 128 + (s & 7));
}
__device__ __forceinline__ int voff_d(int d) {
  return ((d >> 4) & 3) * 1024 + (d & 15) * 8;
}

// ---------------- fp32 -> bf16 convert ----------------
__global__ void conv_f2b(const float* __restrict__ in, u16* __restrict__ out, int n4) {
  int i = blockIdx.x * blockDim.x + threadIdx.x;
  if (i >= n4) return;
  f4 v = ((const f4*)in)[i];
  ushort4 o;
  o.x = f2bf(v[0]); o.y = f2bf(v[1]); o.z = f2bf(v[2]); o.w = f2bf(v[3]);
  ((ushort4*)out)[i] = o;
}

// ---------------- 128x128 MFMA GEMM: Q-projection (2-phase dbuf, BK=64) ----------------
// LDS layout: [dbuf][khalf][128][32] u16 for A and B.
// RoPE + 1/8 scale, bf16 out0[(head*S + s)*64 + d], head = col/64
__global__ __launch_bounds__(256) void gemm128(
    const u16* __restrict__ A, const u16* __restrict__ W,
    const float* __restrict__ bias, int K,
    u16* __restrict__ out0) {
  __shared__ __align__(16) u16 As[2 * 2 * 128 * 32];
  __shared__ __align__(16) u16 Bs[2 * 2 * 128 * 32];
  int t = threadIdx.x, w = t >> 6, L = t & 63;
  int lm = L & 15, quad = L >> 4;
  int m0 = blockIdx.x * 128, n0 = blockIdx.y * 128;
  int wm = w >> 1, wn = w & 1;
  int srow = L >> 2, scol8 = (L & 3) * 8;
  const u16* Ag0 = A + (size_t)(m0 + (w * 2) * 16 + srow) * K + scol8;
  const u16* Ag1 = Ag0 + (size_t)16 * K;
  const u16* Wg0 = W + (size_t)(n0 + (w * 2) * 16 + srow) * K + scol8;
  const u16* Wg1 = Wg0 + (size_t)16 * K;
  u16* lA0 = &As[(w * 2) * 512];
  u16* lA1 = &As[(w * 2 + 1) * 512];
  u16* lB0 = &Bs[(w * 2) * 512];
  u16* lB1 = &Bs[(w * 2 + 1) * 512];
  f32x4 acc[4][4] = {};
  int nk = K >> 6;   // BK = 64
  // prologue: stage K-tile 0 (both 32-halves) into buffer 0
  GLOAD_LDS(Ag0, lA0);           GLOAD_LDS(Ag1, lA1);
  GLOAD_LDS(Ag0 + 32, lA0 + 4096); GLOAD_LDS(Ag1 + 32, lA1 + 4096);
  GLOAD_LDS(Wg0, lB0);           GLOAD_LDS(Wg1, lB1);
  GLOAD_LDS(Wg0 + 32, lB0 + 4096); GLOAD_LDS(Wg1 + 32, lB1 + 4096);
  Ag0 += 64; Ag1 += 64; Wg0 += 64; Wg1 += 64;
  __syncthreads();
  for (int kt = 0; kt < nk; ++kt) {
    int cur = (kt & 1) << 13;     // 8192 u16 per dbuf slot
    int nxt = 8192 - cur;
    if (kt + 1 < nk) {
      GLOAD_LDS(Ag0, lA0 + nxt);           GLOAD_LDS(Ag1, lA1 + nxt);
      GLOAD_LDS(Ag0 + 32, lA0 + nxt + 4096); GLOAD_LDS(Ag1 + 32, lA1 + nxt + 4096);
      GLOAD_LDS(Wg0, lB0 + nxt);           GLOAD_LDS(Wg1, lB1 + nxt);
      GLOAD_LDS(Wg0 + 32, lB0 + nxt + 4096); GLOAD_LDS(Wg1 + 32, lB1 + nxt + 4096);
      Ag0 += 64; Ag1 += 64; Wg0 += 64; Wg1 += 64;
    }
#pragma unroll
    for (int h = 0; h < 2; ++h) {
      int base = cur + h * 4096;
      bf16x8 af[4], bf[4];
#pragma unroll
      for (int i = 0; i < 4; ++i) af[i] = *(const bf16x8*)&As[base + (wm * 64 + i * 16 + lm) * 32 + quad * 8];
#pragma unroll
      for (int j = 0; j < 4; ++j) bf[j] = *(const bf16x8*)&Bs[base + (wn * 64 + j * 16 + lm) * 32 + quad * 8];
#pragma unroll
      for (int i = 0; i < 4; ++i)
#pragma unroll
        for (int j = 0; j < 4; ++j)
          acc[i][j] = __builtin_amdgcn_mfma_f32_16x16x32_bf16(af[i], bf[j], acc[i][j], 0, 0, 0);
    }
    __syncthreads();
  }
  int head = (n0 + wn * 64) >> 6;
  float b0v = bias[head * 64 + lm];
  float b1v = bias[head * 64 + 16 + lm];
  float b2v = bias[head * 64 + 32 + lm];
  float b3v = bias[head * 64 + 48 + lm];
  float invf1 = __expf(-(float)lm * RLN);
  float invf2 = __expf(-(float)(lm + 16) * RLN);
#pragma unroll
  for (int i = 0; i < 4; ++i) {
    int sq = m0 + wm * 64 + i * 16 + quad * 4;
#pragma unroll
    for (int r = 0; r < 4; ++r) {
      float a0 = acc[i][0][r] + b0v, a1 = acc[i][1][r] + b1v;
      float a2 = acc[i][2][r] + b2v, a3 = acc[i][3][r] + b3v;
      float s1, c1, s2, c2;
      sincosf((float)(sq + r) * invf1, &s1, &c1);
      sincosf((float)(sq + r) * invf2, &s2, &c2);
      u16* op = out0 + ((size_t)head * S_LEN + sq + r) * HD;
      op[lm]      = f2bf((a0 * c1 - a2 * s1) * 0.125f);
      op[lm + 32] = f2bf((a2 * c1 + a0 * s1) * 0.125f);
      op[lm + 16] = f2bf((a1 * c2 - a3 * s2) * 0.125f);
      op[lm + 48] = f2bf((a3 * c2 + a1 * s2) * 0.125f);
    }
  }
}

// ---------------- 64x128 MFMA GEMM: O-projection (2-phase dbuf, BK=64, fp32 out + bias) ----------------
// LDS layout: A [dbuf][khalf][64][32], B [dbuf][khalf][128][32].
__global__ __launch_bounds__(256) void gemm64(
    const u16* __restrict__ A, const u16* __restrict__ W,
    const float* __restrict__ bias, int K, int Nreal,
    float* __restrict__ out) {
  __shared__ __align__(16) u16 As[2 * 2 * 64 * 32];
  __shared__ __align__(16) u16 Bs[2 * 2 * 128 * 32];
  int t = threadIdx.x, w = t >> 6, L = t & 63;
  int lm = L & 15, quad = L >> 4;
  int m0 = blockIdx.x * 64, n0 = blockIdx.y * 128;
  int wm = w >> 1, wn = w & 1;
  int srow = L >> 2, scol8 = (L & 3) * 8;
  const u16* Ag = A + (size_t)(m0 + w * 16 + srow) * K + scol8;
  int wr0 = n0 + w * 16 + srow;      if (wr0 > Nreal - 1) wr0 = Nreal - 1;
  int wr1 = n0 + 64 + w * 16 + srow; if (wr1 > Nreal - 1) wr1 = Nreal - 1;
  const u16* Wg0 = W + (size_t)wr0 * K + scol8;
  const u16* Wg1 = W + (size_t)wr1 * K + scol8;
  u16* lA  = &As[w * 512];
  u16* lB0 = &Bs[w * 512];
  u16* lB1 = &Bs[2048 + w * 512];
  f32x4 acc[2][4] = {};
  int nk = K >> 6;   // BK = 64
  // prologue: stage K-tile 0 (both 32-halves) into buffer 0
  GLOAD_LDS(Ag, lA);            GLOAD_LDS(Ag + 32, lA + 2048);
  GLOAD_LDS(Wg0, lB0);          GLOAD_LDS(Wg0 + 32, lB0 + 4096);
  GLOAD_LDS(Wg1, lB1);          GLOAD_LDS(Wg1 + 32, lB1 + 4096);
  Ag += 64; Wg0 += 64; Wg1 += 64;
  __syncthreads();
  for (int kt = 0; kt < nk; ++kt) {
    int curA = (kt & 1) << 12;    // 4096 u16 per A dbuf slot
    int curB = (kt & 1) << 13;    // 8192 u16 per B dbuf slot
    int nxtA = 4096 - curA, nxtB = 8192 - curB;
    if (kt + 1 < nk) {
      GLOAD_LDS(Ag, lA + nxtA);          GLOAD_LDS(Ag + 32, lA + nxtA + 2048);
      GLOAD_LDS(Wg0, lB0 + nxtB);        GLOAD_LDS(Wg0 + 32, lB0 + nxtB + 4096);
      GLOAD_LDS(Wg1, lB1 + nxtB);        GLOAD_LDS(Wg1 + 32, lB1 + nxtB + 4096);
      Ag += 64; Wg0 += 64; Wg1 += 64;
    }
#pragma unroll
    for (int h = 0; h < 2; ++h) {
      int baseA = curA + h * 2048;
      int baseB = curB + h * 4096;
      bf16x8 af[2], bf[4];
#pragma unroll
      for (int i = 0; i < 2; ++i) af[i] = *(const bf16x8*)&As[baseA + (wm * 32 + i * 16 + lm) * 32 + quad * 8];
#pragma unroll
      for (int j = 0; j < 4; ++j) bf[j] = *(const bf16x8*)&Bs[baseB + (wn * 64 + j * 16 + lm) * 32 + quad * 8];
#pragma unroll
      for (int i = 0; i < 2; ++i)
#pragma unroll
        for (int j = 0; j < 4; ++j)
          acc[i][j] = __builtin_amdgcn_mfma_f32_16x16x32_bf16(af[i], bf[j], acc[i][j], 0, 0, 0);
    }
    __syncthreads();
  }
#pragma unroll
  for (int i = 0; i < 2; ++i) {
#pragma unroll
    for (int r = 0; r < 4; ++r) {
      int row = m0 + wm * 32 + i * 16 + quad * 4 + r;
#pragma unroll
      for (int j = 0; j < 4; ++j) {
        int col = n0 + wn * 64 + j * 16 + lm;
        if (col < Nreal)
          out[(size_t)row * Nreal + col] = acc[i][j][r] + bias[col];
      }
    }
  }
}

// ---------------- 64x64 MFMA GEMM for the two small KV GEMMs ----------------
// mode 2: KV: even n-tiles = K half (RoPE -> fragment-linear K layout),
//             odd = V half (-> fragment-linear V^T layout), kvh = n0/128
// mode 3: bf16 row-major out0
__global__ __launch_bounds__(256) void gemm_bt(
    const u16* __restrict__ A, const u16* __restrict__ W,
    int M, int N, int K, int mode,
    u16* __restrict__ out0, u16* __restrict__ out1) {
  __shared__ __align__(16) u16 As[64 * 32];
  __shared__ __align__(16) u16 Bs[64 * 32];
  int t = threadIdx.x;
  int m0 = blockIdx.x * 64, n0 = blockIdx.y * 64;
  int w = t >> 6, L = t & 63;
  int srow = t >> 2, scol = (t & 3) * 8;
  int lm = L & 15, quad = L >> 4;
  const u16* Ap = A + (size_t)(m0 + srow) * K + scol;
  const u16* Wp = W + (size_t)(n0 + srow) * K + scol;
  f32x4 acc0 = {0.f, 0.f, 0.f, 0.f}, acc1 = acc0, acc2 = acc0, acc3 = acc0;
  int aoff = (w * 16 + lm) * 32 + quad * 8;
  int boff = lm * 32 + quad * 8;
  int nk = K >> 5;
  uint4 av = *(const uint4*)Ap;
  uint4 wv = *(const uint4*)Wp;
  for (int kt = 0; kt < nk; ++kt) {
    *(uint4*)&As[srow * 32 + scol] = av;
    *(uint4*)&Bs[srow * 32 + scol] = wv;
    __syncthreads();
    if (kt + 1 < nk) {
      Ap += 32; Wp += 32;
      av = *(const uint4*)Ap;
      wv = *(const uint4*)Wp;
    }
    bf16x8 af = *(const bf16x8*)&As[aoff];
    bf16x8 b0 = *(const bf16x8*)&Bs[boff];
    bf16x8 b1 = *(const bf16x8*)&Bs[boff + 16 * 32];
    bf16x8 b2 = *(const bf16x8*)&Bs[boff + 32 * 32];
    bf16x8 b3 = *(const bf16x8*)&Bs[boff + 48 * 32];
    acc0 = __builtin_amdgcn_mfma_f32_16x16x32_bf16(af, b0, acc0, 0, 0, 0);
    acc1 = __builtin_amdgcn_mfma_f32_16x16x32_bf16(af, b1, acc1, 0, 0, 0);
    acc2 = __builtin_amdgcn_mfma_f32_16x16x32_bf16(af, b2, acc2, 0, 0, 0);
    acc3 = __builtin_amdgcn_mfma_f32_16x16x32_bf16(af, b3, acc3, 0, 0, 0);
    __syncthreads();
  }
  int mbase = m0 + w * 16 + quad * 4;
  if (mode == 3) {
    for (int r = 0; r < 4; ++r) {
      int row = mbase + r;
      float vals[4] = {acc0[r], acc1[r], acc2[r], acc3[r]};
      for (int nt = 0; nt < 4; ++nt)
        out0[(size_t)row * N + (n0 + nt * 16 + lm)] = f2bf(vals[nt]);
    }
  } else {
    bool isV = ((blockIdx.y & 1) == 1);
    int head = (n0 >> 7);
    size_t hb = (size_t)head << 17;
    if (isV) {
      // V -> fragment-linear V^T layout
      int dof[4];
#pragma unroll
      for (int nt = 0; nt < 4; ++nt) dof[nt] = voff_d(nt * 16 + lm);
      for (int r = 0; r < 4; ++r) {
        int s = mbase + r;
        size_t so = hb + voff_s(s);
        float vals[4] = {acc0[r], acc1[r], acc2[r], acc3[r]};
#pragma unroll
        for (int nt = 0; nt < 4; ++nt)
          out1[so + dof[nt]] = f2bf(vals[nt]);
      }
    } else {
      // K -> RoPE -> fragment-linear K layout
      int d0 = koff_d(lm), d1 = koff_d(lm + 16), d2 = koff_d(lm + 32), d3 = koff_d(lm + 48);
      float invf1 = __expf(-(float)lm * RLN);
      float invf2 = __expf(-(float)(lm + 16) * RLN);
      for (int r = 0; r < 4; ++r) {
        int s = mbase + r;
        float a0 = acc0[r], a1 = acc1[r], a2 = acc2[r], a3 = acc3[r];
        float s1, c1, s2, c2;
        sincosf((float)s * invf1, &s1, &c1);
        sincosf((float)s * invf2, &s2, &c2);
        size_t so = hb + koff_s(s);
        out0[so + d0] = f2bf(a0 * c1 - a2 * s1);
        out0[so + d2] = f2bf(a2 * c1 + a0 * s1);
        out0[so + d1] = f2bf(a1 * c2 - a3 * s2);
        out0[so + d3] = f2bf(a3 * c2 + a1 * s2);
      }
    }
  }
}

// ---------------- MFMA flash attention v5 ----------------
// R3 structure (K loaded at loop top, short live range — R4's prefetch
// rotation spilled to scratch: +37MB FETCH/+37MB WRITE) plus:
// (a) v_cvt_pk_bf16_f32 for P packing, (b) defer-max (THR=8),
// (c) s_setprio(1/0) around MFMA clusters (T5).
__global__ __launch_bounds__(256, 4) void attn_v3(
    const u16* __restrict__ Qb, const u16* __restrict__ Kf,
    const u16* __restrict__ Vf, u16* __restrict__ attnb) {
  __shared__ __align__(16) u16 Ps[4 * 16 * 72];  // per-wave P, row stride 72 u16
  int t = threadIdx.x;
  int w = t >> 6, L = t & 63;
  int lm = L & 15, quad = L >> 4;
  int bx = blockIdx.x, h = blockIdx.y, kvh = h >> 3;
  u16* pw = &Ps[w * 16 * 72];
  const u16* Kbase = Kf + ((size_t)kvh << 17) + L * 8;
  const u16* Vbase = Vf + ((size_t)kvh << 17) + L * 8;

  for (int ph = 0; ph < 2; ++ph) {
    int qt = ph ? (31 - bx) : bx;
    int q0 = qt * 64;
    // Q B-fragments: lane holds Q[q0+w*16+lm][quad*8+e] (halves 0/1)
    const u16* Qp = Qb + ((size_t)h * S_LEN + q0 + w * 16 + lm) * HD + quad * 8;
    bf16x8 qf0 = *(const bf16x8*)Qp;
    bf16x8 qf1 = *(const bf16x8*)(Qp + 32);
    f32x4 o[4] = {};
    float m_ = -3.0e38f, l_ = 0.f;

    for (int c = 0; c <= qt; ++c) {
      const u16* Kc = Kbase + (size_t)c * 4096;
      // ---- K fragments: contiguous 1KB wave loads ----
      bf16x8 kfa[4], kfb[4];
#pragma unroll
      for (int j = 0; j < 4; ++j) {
        kfa[j] = *(const bf16x8*)(Kc + j * 1024);
        kfb[j] = *(const bf16x8*)(Kc + j * 1024 + 512);
      }
      // ---- S^T = K Q^T : tile j rows kv=j*16+quad*4+r, col q=lm ----
      f32x4 st[4] = {};
      __builtin_amdgcn_s_setprio(1);
#pragma unroll
      for (int j = 0; j < 4; ++j) {
        st[j] = __builtin_amdgcn_mfma_f32_16x16x32_bf16(kfa[j], qf0, st[j], 0, 0, 0);
        st[j] = __builtin_amdgcn_mfma_f32_16x16x32_bf16(kfb[j], qf1, st[j], 0, 0, 0);
      }
      __builtin_amdgcn_s_setprio(0);
      // ---- V fragments issued now (consumed after softmax) ----
      const u16* Vc = Vbase + (size_t)c * 4096;
      bf16x8 vfa[4], vfb[4];
#pragma unroll
      for (int j = 0; j < 4; ++j) {
        vfa[j] = *(const bf16x8*)(Vc + j * 1024);
        vfb[j] = *(const bf16x8*)(Vc + j * 1024 + 512);
      }
      // ---- causal mask on diagonal chunk ----
      if (c == qt) {
        int qloc = w * 16 + lm;
#pragma unroll
        for (int j = 0; j < 4; ++j) {
          int kvb = j * 16 + quad * 4;
#pragma unroll
          for (int r = 0; r < 4; ++r)
            if (kvb + r > qloc) st[j][r] = -3.0e38f;
        }
      }
      // ---- online softmax: each lane owns 16 scores of q-row lm ----
      float mloc = -3.0e38f;
#pragma unroll
      for (int j = 0; j < 4; ++j)
        mloc = fmaxf(mloc, fmaxf(fmaxf(st[j][0], st[j][1]), fmaxf(st[j][2], st[j][3])));
      mloc = fmaxf(mloc, __shfl_xor(mloc, 16));
      mloc = fmaxf(mloc, __shfl_xor(mloc, 32));
      float mn;
      if (__all(mloc - m_ <= 8.f)) {
        // defer: keep old max, no O/l rescale (P bounded by e^8)
        mn = m_;
      } else {
        mn = fmaxf(m_, mloc);
        float al = __expf(m_ - mn);
        m_ = mn;
        l_ *= al;
        float a0 = __shfl(al, quad * 4 + 0);
        float a1 = __shfl(al, quad * 4 + 1);
        float a2 = __shfl(al, quad * 4 + 2);
        float a3 = __shfl(al, quad * 4 + 3);
#pragma unroll
        for (int j = 0; j < 4; ++j) {
          o[j][0] *= a0; o[j][1] *= a1; o[j][2] *= a2; o[j][3] *= a3;
        }
      }
      float sum = 0.f;
      u16* pws = pw + lm * 72;
#pragma unroll
      for (int j = 0; j < 4; ++j) {
        float p0 = __expf(st[j][0] - mn);
        float p1 = __expf(st[j][1] - mn);
        float p2 = __expf(st[j][2] - mn);
        float p3 = __expf(st[j][3] - mn);
        sum += (p0 + p1) + (p2 + p3);
        uint2 pk;
        asm("v_cvt_pk_bf16_f32 %0, %1, %2" : "=v"(pk.x) : "v"(p0), "v"(p1));
        asm("v_cvt_pk_bf16_f32 %0, %1, %2" : "=v"(pk.y) : "v"(p2), "v"(p3));
        *(uint2*)(pws + j * 16 + quad * 4) = pk;
      }
      l_ += sum;
      // ---- P (A-layout) from LDS ----
      bf16x8 pa = *(const bf16x8*)(pw + lm * 72 + quad * 8);
      bf16x8 pb = *(const bf16x8*)(pw + lm * 72 + 32 + quad * 8);
      // ---- O += P V ----
      __builtin_amdgcn_s_setprio(1);
#pragma unroll
      for (int j = 0; j < 4; ++j) {
        o[j] = __builtin_amdgcn_mfma_f32_16x16x32_bf16(pa, vfa[j], o[j], 0, 0, 0);
        o[j] = __builtin_amdgcn_mfma_f32_16x16x32_bf16(pb, vfb[j], o[j], 0, 0, 0);
      }
      __builtin_amdgcn_s_setprio(0);
    }
    // ---- finalize ----
    l_ += __shfl_xor(l_, 16);
    l_ += __shfl_xor(l_, 32);
    float linv = 1.0f / l_;
    float li0 = __shfl(linv, quad * 4 + 0);
    float li1 = __shfl(linv, quad * 4 + 1);
    float li2 = __shfl(linv, quad * 4 + 2);
    float li3 = __shfl(linv, quad * 4 + 3);
#pragma unroll
    for (int r = 0; r < 4; ++r) {
      float lr = (r == 0) ? li0 : (r == 1) ? li1 : (r == 2) ? li2 : li3;
      int row = q0 + w * 16 + quad * 4 + r;
      u16* op = attnb + (size_t)row * NQD + h * HD;
      op[lm]      = f2bf(o[0][r] * lr);
      op[lm + 16] = f2bf(o[1][r] * lr);
      op[lm + 32] = f2bf(o[2][r] * lr);
      op[lm + 48] = f2bf(o[3][r] * lr);
    }
  }
}

extern "C" void kernel_launch(void* const* d_in, const int* in_sizes, int n_in,
                              void* d_out, int out_size, void* d_ws, size_t ws_size,
                              hipStream_t stream) {
  (void)in_sizes; (void)n_in; (void)out_size; (void)ws_size;
  const float* hidden = (const float*)d_in[0];
  // d_in[1] = attention_mask (exactly causal; handled analytically)
  const float* q_w    = (const float*)d_in[2];
  const float* q_b    = (const float*)d_in[3];
  const float* kv_a_w = (const float*)d_in[4];
  const float* kv_b_w = (const float*)d_in[5];
  const float* o_w    = (const float*)d_in[6];
  const float* o_b    = (const float*)d_in[7];

  char* ws = (char*)d_ws;
  u16* hb    = (u16*)(ws + 0);           // 2048x2880
  u16* qwb   = (u16*)(ws + 11796480);    // 4096x2880
  u16* kab   = (u16*)(ws + 35389440);    // 384x2880
  u16* kbb   = (u16*)(ws + 37601280);    // 1024x384
  u16* owb   = (u16*)(ws + 38387712);    // 2880x4096
  u16* Qb    = (u16*)(ws + 61980672);    // (64,2048,64) roped, pre-scaled 1/8
  u16* CKVb  = (u16*)(ws + 78757888);    // 2048x384
  u16* Kfb   = (u16*)(ws + 80330752);    // (8) fragment-linear K, 2MB
  u16* Vfb   = (u16*)(ws + 82427904);    // (8) fragment-linear V^T, 2MB
  u16* attnb = (u16*)(ws + 84525056);    // 2048x4096

  conv_f2b<<<(1474560 + 255) / 256, 256, 0, stream>>>(hidden, hb, 1474560);
  conv_f2b<<<(2949120 + 255) / 256, 256, 0, stream>>>(q_w, qwb, 2949120);
  conv_f2b<<<(276480 + 255) / 256, 256, 0, stream>>>(kv_a_w, kab, 276480);
  conv_f2b<<<(98304 + 255) / 256, 256, 0, stream>>>(kv_b_w, kbb, 98304);
  conv_f2b<<<(2949120 + 255) / 256, 256, 0, stream>>>(o_w, owb, 2949120);

  gemm128<<<dim3(16, 32), 256, 0, stream>>>(hb, qwb, q_b, H_DIM, Qb);
  gemm_bt<<<dim3(32, 6),  256, 0, stream>>>(hb, kab, S_LEN, RANKD, H_DIM, 3, CKVb, nullptr);
  gemm_bt<<<dim3(32, 16), 256, 0, stream>>>(CKVb, kbb, S_LEN, 1024, RANKD, 2, Kfb, Vfb);
  attn_v3<<<dim3(16, 64), 256, 0, stream>>>(Qb, Kfb, Vfb, attnb);
  gemm64<<<dim3(32, 23), 256, 0, stream>>>(attnb, owb, o_b, NQD, H_DIM, (float*)d_out);
}